// Round 1
// baseline (1522.952 us; speedup 1.0000x reference)
//
#include <hip/hip_runtime.h>
#include <stdint.h>
#include <stddef.h>

#define NTOK 8192
#define DM 1024
#define DF 4096
#define NE 8
#define TM 128
#define TN 128
#define BK 64

typedef unsigned short u16;
typedef __attribute__((ext_vector_type(8))) short bf16x8;
typedef __attribute__((ext_vector_type(4))) float f32x4;

__device__ __forceinline__ u16 f2bf(float f) {
  union { float f; unsigned u; } v; v.f = f;
  unsigned r = v.u + 0x7fffu + ((v.u >> 16) & 1u);
  return (u16)(r >> 16);
}

__device__ __forceinline__ void async_copy16(const void* g, void* l) {
  __builtin_amdgcn_global_load_lds((const __attribute__((address_space(1))) void*)g,
                                   (__attribute__((address_space(3))) void*)l, 16, 0, 0);
}

// ---------- cast x (fp32 -> bf16), 4 elems/thread ----------
__global__ __launch_bounds__(256) void k_cast_x(const float* __restrict__ x, u16* __restrict__ xb) {
  int i = (blockIdx.x * 256 + threadIdx.x) * 4;
  float4 v = *(const float4*)(x + i);
  ushort4 o;
  o.x = f2bf(v.x); o.y = f2bf(v.y); o.z = f2bf(v.z); o.w = f2bf(v.w);
  *(ushort4*)(xb + i) = o;
}

// ---------- transpose + cast weights: w [E][R][C] fp32 -> wt [E][C][R] bf16 ----------
__global__ __launch_bounds__(256) void k_transpose_cast(const float* __restrict__ w, u16* __restrict__ wt,
                                                        int R, int C) {
  __shared__ float tile[32][33];
  size_t base = (size_t)blockIdx.z * R * C;
  const float* wb = w + base;
  u16* wtb = wt + base;
  int c0 = blockIdx.x * 32, r0 = blockIdx.y * 32;
  int tx = threadIdx.x & 31, ty = threadIdx.x >> 5;
#pragma unroll
  for (int i = 0; i < 4; i++)
    tile[ty + i * 8][tx] = wb[(size_t)(r0 + ty + i * 8) * C + (c0 + tx)];
  __syncthreads();
#pragma unroll
  for (int i = 0; i < 4; i++)
    wtb[(size_t)(c0 + ty + i * 8) * R + (r0 + tx)] = f2bf(tile[tx][ty + i * 8]);
}

// ---------- gating: fp32 logits, softmax, top-2, routing lists ----------
__global__ __launch_bounds__(256) void k_gate(const float* __restrict__ x, const float* __restrict__ gw,
                                              const float* __restrict__ gb, int* __restrict__ cnt,
                                              int* __restrict__ lidx, float* __restrict__ lw) {
  int wave = threadIdx.x >> 6, lane = threadIdx.x & 63;
  int tok = blockIdx.x * 4 + wave;
  const float* xr = x + (size_t)tok * DM;
  float acc[NE];
#pragma unroll
  for (int e = 0; e < NE; e++) acc[e] = 0.f;
  for (int d = lane; d < DM; d += 64) {
    float xv = xr[d];
    const float* g = gw + d * NE;
#pragma unroll
    for (int e = 0; e < NE; e++) acc[e] += xv * g[e];
  }
#pragma unroll
  for (int off = 32; off > 0; off >>= 1) {
#pragma unroll
    for (int e = 0; e < NE; e++) acc[e] += __shfl_down(acc[e], off);
  }
  if (lane == 0) {
    float l[NE], m = -1e30f;
#pragma unroll
    for (int e = 0; e < NE; e++) { l[e] = acc[e] + gb[e]; m = l[e] > m ? l[e] : m; }
    float p[NE], s = 0.f;
#pragma unroll
    for (int e = 0; e < NE; e++) { p[e] = expf(l[e] - m); s += p[e]; }
    float inv = 1.f / s;
    int e0 = 0; float s0 = p[0];
#pragma unroll
    for (int e = 1; e < NE; e++) if (p[e] > s0) { s0 = p[e]; e0 = e; }
    int e1 = -1; float s1 = -1.f;
#pragma unroll
    for (int e = 0; e < NE; e++) if (e != e0 && p[e] > s1) { s1 = p[e]; e1 = e; }
    s0 *= inv; s1 *= inv;
    int pos0 = atomicAdd(&cnt[e0], 1);
    lidx[e0 * NTOK + pos0] = tok; lw[e0 * NTOK + pos0] = s0;
    int pos1 = atomicAdd(&cnt[e1], 1);
    lidx[e1 * NTOK + pos1] = tok; lw[e1 * NTOK + pos1] = s1;
  }
}

__global__ void k_scan(const int* __restrict__ cnt, int* __restrict__ off) {
  if (threadIdx.x == 0) {
    int s = 0;
    for (int e = 0; e < NE; e++) { off[e] = s; s += cnt[e]; }
  }
}

// ---------- GEMM1: H[pair, f] = relu(Xb[idx] @ W1t^T + b1)  (K = DM) ----------
__global__ __launch_bounds__(256) void k_gemm1(const u16* __restrict__ xb, const u16* __restrict__ w1t,
                                               const float* __restrict__ b1, u16* __restrict__ H,
                                               const int* __restrict__ cnt, const int* __restrict__ offp,
                                               const int* __restrict__ lidx) {
  const int e = blockIdx.z;
  const int c = cnt[e];
  const int t0 = blockIdx.x * TM;
  if (t0 >= c) return;
  const int n0 = blockIdx.y * TN;

  __shared__ __align__(16) u16 smA[TM * BK];
  __shared__ __align__(16) u16 smB[TN * BK];

  const int tid = threadIdx.x;
  const int wave = tid >> 6, lane = tid & 63;
  const int sr = lane >> 3;
  const int skb = (lane & 7) * 8;

  const u16* aPtr[4]; const u16* bPtr[4];
#pragma unroll
  for (int i = 0; i < 4; i++) {
    int ci = wave * 4 + i;
    int row = ci * 8 + sr;
    int p = t0 + row; p = p < c ? p : c - 1;
    int tk = lidx[e * NTOK + p];
    aPtr[i] = xb + (size_t)tk * DM + skb;
    bPtr[i] = w1t + ((size_t)e * DF + (n0 + row)) * DM + skb;
  }

  const int waveM = wave >> 1, waveN = wave & 1;
  const int c15 = lane & 15, quad = lane >> 4;

  f32x4 acc[4][4];
#pragma unroll
  for (int mt = 0; mt < 4; mt++)
#pragma unroll
    for (int nt = 0; nt < 4; nt++) acc[mt][nt] = 0.f;

  for (int k0 = 0; k0 < DM; k0 += BK) {
#pragma unroll
    for (int i = 0; i < 4; i++) {
      async_copy16(aPtr[i], &smA[(wave * 4 + i) * 512]);
      async_copy16(bPtr[i], &smB[(wave * 4 + i) * 512]);
      aPtr[i] += BK; bPtr[i] += BK;
    }
    __syncthreads();
#pragma unroll
    for (int k2 = 0; k2 < BK; k2 += 32) {
      bf16x8 af[4], bfr[4];
#pragma unroll
      for (int mt = 0; mt < 4; mt++)
        af[mt] = *(const bf16x8*)&smA[(waveM * 64 + mt * 16 + c15) * BK + k2 + quad * 8];
#pragma unroll
      for (int nt = 0; nt < 4; nt++)
        bfr[nt] = *(const bf16x8*)&smB[(waveN * 64 + nt * 16 + c15) * BK + k2 + quad * 8];
#pragma unroll
      for (int mt = 0; mt < 4; mt++)
#pragma unroll
        for (int nt = 0; nt < 4; nt++)
          acc[mt][nt] = __builtin_amdgcn_mfma_f32_16x16x32_bf16(af[mt], bfr[nt], acc[mt][nt], 0, 0, 0);
    }
    __syncthreads();
  }

  const int hoff = offp[e];
#pragma unroll
  for (int mt = 0; mt < 4; mt++) {
#pragma unroll
    for (int r = 0; r < 4; r++) {
      int rowLoc = waveM * 64 + mt * 16 + quad * 4 + r;
      int p = t0 + rowLoc;
      if (p < c) {
        size_t hbase = (size_t)(hoff + p) * DF;
#pragma unroll
        for (int nt = 0; nt < 4; nt++) {
          int col = n0 + waveN * 64 + nt * 16 + c15;
          float v = acc[mt][nt][r] + b1[e * DF + col];
          H[hbase + col] = f2bf(v > 0.f ? v : 0.f);
        }
      }
    }
  }
}

// ---------- GEMM2: out[tok, d] += s * (H @ W2t^T + b2)  (K = DF) ----------
__global__ __launch_bounds__(256) void k_gemm2(const u16* __restrict__ H, const u16* __restrict__ w2t,
                                               const float* __restrict__ b2, float* __restrict__ out,
                                               const int* __restrict__ cnt, const int* __restrict__ offp,
                                               const int* __restrict__ lidx, const float* __restrict__ lw) {
  const int e = blockIdx.z;
  const int c = cnt[e];
  const int t0 = blockIdx.x * TM;
  if (t0 >= c) return;
  const int n0 = blockIdx.y * TN;
  const int hoff = offp[e];

  __shared__ __align__(16) u16 smA[TM * BK];
  __shared__ __align__(16) u16 smB[TN * BK];

  const int tid = threadIdx.x;
  const int wave = tid >> 6, lane = tid & 63;
  const int sr = lane >> 3;
  const int skb = (lane & 7) * 8;

  const u16* aPtr[4]; const u16* bPtr[4];
#pragma unroll
  for (int i = 0; i < 4; i++) {
    int ci = wave * 4 + i;
    int row = ci * 8 + sr;
    int p = t0 + row; p = p < c ? p : c - 1;
    aPtr[i] = H + (size_t)(hoff + p) * DF + skb;
    bPtr[i] = w2t + ((size_t)e * DM + (n0 + row)) * DF + skb;
  }

  const int waveM = wave >> 1, waveN = wave & 1;
  const int c15 = lane & 15, quad = lane >> 4;

  f32x4 acc[4][4];
#pragma unroll
  for (int mt = 0; mt < 4; mt++)
#pragma unroll
    for (int nt = 0; nt < 4; nt++) acc[mt][nt] = 0.f;

  for (int k0 = 0; k0 < DF; k0 += BK) {
#pragma unroll
    for (int i = 0; i < 4; i++) {
      async_copy16(aPtr[i], &smA[(wave * 4 + i) * 512]);
      async_copy16(bPtr[i], &smB[(wave * 4 + i) * 512]);
      aPtr[i] += BK; bPtr[i] += BK;
    }
    __syncthreads();
#pragma unroll
    for (int k2 = 0; k2 < BK; k2 += 32) {
      bf16x8 af[4], bfr[4];
#pragma unroll
      for (int mt = 0; mt < 4; mt++)
        af[mt] = *(const bf16x8*)&smA[(waveM * 64 + mt * 16 + c15) * BK + k2 + quad * 8];
#pragma unroll
      for (int nt = 0; nt < 4; nt++)
        bfr[nt] = *(const bf16x8*)&smB[(waveN * 64 + nt * 16 + c15) * BK + k2 + quad * 8];
#pragma unroll
      for (int mt = 0; mt < 4; mt++)
#pragma unroll
        for (int nt = 0; nt < 4; nt++)
          acc[mt][nt] = __builtin_amdgcn_mfma_f32_16x16x32_bf16(af[mt], bfr[nt], acc[mt][nt], 0, 0, 0);
    }
    __syncthreads();
  }

#pragma unroll
  for (int mt = 0; mt < 4; mt++) {
#pragma unroll
    for (int r = 0; r < 4; r++) {
      int rowLoc = waveM * 64 + mt * 16 + quad * 4 + r;
      int p = t0 + rowLoc;
      if (p < c) {
        int tok = lidx[e * NTOK + p];
        float wgt = lw[e * NTOK + p];
#pragma unroll
        for (int nt = 0; nt < 4; nt++) {
          int col = n0 + waveN * 64 + nt * 16 + c15;
          float v = wgt * (acc[mt][nt][r] + b2[e * DM + col]);
          atomicAdd(&out[(size_t)tok * DM + col], v);
        }
      }
    }
  }
}

extern "C" void kernel_launch(void* const* d_in, const int* in_sizes, int n_in,
                              void* d_out, int out_size, void* d_ws, size_t ws_size,
                              hipStream_t stream) {
  const float* x  = (const float*)d_in[0];
  const float* gw = (const float*)d_in[1];
  const float* gb = (const float*)d_in[2];
  const float* w1 = (const float*)d_in[3];
  const float* b1 = (const float*)d_in[4];
  const float* w2 = (const float*)d_in[5];
  const float* b2 = (const float*)d_in[6];
  float* out = (float*)d_out;

  char* ws = (char*)d_ws;
  // layout: xb (16 MiB) | wT (64 MiB, shared by w1t then w2t) | H (128 MiB) | lidx | lw | cnt | off
  u16* xb    = (u16*)(ws);
  u16* wT    = (u16*)(ws + 16777216);
  u16* H     = (u16*)(ws + 16777216 + 67108864);
  int* lidx  = (int*)(ws + 16777216 + 67108864 + 134217728);
  float* lw  = (float*)(ws + 16777216 + 67108864 + 134217728 + 262144);
  int* cnt   = (int*)(ws + 16777216 + 67108864 + 134217728 + 262144 + 262144);
  int* offp  = (int*)(ws + 16777216 + 67108864 + 134217728 + 262144 + 262144 + 128);

  hipMemsetAsync(cnt, 0, NE * sizeof(int), stream);
  hipMemsetAsync(out, 0, (size_t)out_size * sizeof(float), stream);

  k_cast_x<<<(NTOK * DM) / 1024, 256, 0, stream>>>(x, xb);
  k_gate<<<NTOK / 4, 256, 0, stream>>>(x, gw, gb, cnt, lidx, lw);
  k_scan<<<1, 64, 0, stream>>>(cnt, offp);

  // W1 [E][DM][DF] -> w1t [E][DF][DM]
  k_transpose_cast<<<dim3(DF / 32, DM / 32, NE), 256, 0, stream>>>(w1, wT, DM, DF);
  k_gemm1<<<dim3(NTOK / TM, DF / TN, NE), 256, 0, stream>>>(xb, wT, b1, H, cnt, offp, lidx);

  // W2 [E][DF][DM] -> w2t [E][DM][DF]  (reuses wT buffer; stream-ordered after gemm1)
  k_transpose_cast<<<dim3(DM / 32, DF / 32, NE), 256, 0, stream>>>(w2, wT, DF, DM);
  k_gemm2<<<dim3(NTOK / TM, DM / TN, NE), 256, 0, stream>>>(H, wT, b2, out, cnt, offp, lidx, lw);
}

// Round 2
// 1348.900 us; speedup vs baseline: 1.1290x; 1.1290x over previous
//
#include <hip/hip_runtime.h>
#include <stdint.h>
#include <stddef.h>

#define NTOK 8192
#define DM 1024
#define DF 4096
#define NE 8
#define TM 128
#define TN 128
#define BK 64

typedef unsigned short u16;
typedef __attribute__((ext_vector_type(8))) short bf16x8;
typedef __attribute__((ext_vector_type(4))) float f32x4;

__device__ __forceinline__ u16 f2bf(float f) {
  union { float f; unsigned u; } v; v.f = f;
  unsigned r = v.u + 0x7fffu + ((v.u >> 16) & 1u);
  return (u16)(r >> 16);
}

__device__ __forceinline__ void async_copy16(const void* g, void* l) {
  __builtin_amdgcn_global_load_lds((const __attribute__((address_space(1))) void*)g,
                                   (__attribute__((address_space(3))) void*)l, 16, 0, 0);
}

// ---------- cast x (fp32 -> bf16), 4 elems/thread ----------
__global__ __launch_bounds__(256) void k_cast_x(const float* __restrict__ x, u16* __restrict__ xb) {
  int i = (blockIdx.x * 256 + threadIdx.x) * 4;
  float4 v = *(const float4*)(x + i);
  ushort4 o;
  o.x = f2bf(v.x); o.y = f2bf(v.y); o.z = f2bf(v.z); o.w = f2bf(v.w);
  *(ushort4*)(xb + i) = o;
}

// ---------- transpose + cast weights: w [E][R][C] fp32 -> wt [E][C][R] bf16 ----------
__global__ __launch_bounds__(256) void k_transpose_cast(const float* __restrict__ w, u16* __restrict__ wt,
                                                        int R, int C) {
  __shared__ float tile[32][33];
  size_t base = (size_t)blockIdx.z * R * C;
  const float* wb = w + base;
  u16* wtb = wt + base;
  int c0 = blockIdx.x * 32, r0 = blockIdx.y * 32;
  int tx = threadIdx.x & 31, ty = threadIdx.x >> 5;
#pragma unroll
  for (int i = 0; i < 4; i++)
    tile[ty + i * 8][tx] = wb[(size_t)(r0 + ty + i * 8) * C + (c0 + tx)];
  __syncthreads();
#pragma unroll
  for (int i = 0; i < 4; i++)
    wtb[(size_t)(c0 + ty + i * 8) * R + (r0 + tx)] = f2bf(tile[tx][ty + i * 8]);
}

// ---------- gating: fp32 logits, softmax, top-2, routing lists ----------
__global__ __launch_bounds__(256) void k_gate(const float* __restrict__ x, const float* __restrict__ gw,
                                              const float* __restrict__ gb, int* __restrict__ cnt,
                                              int* __restrict__ lidx, float* __restrict__ lw) {
  int wave = threadIdx.x >> 6, lane = threadIdx.x & 63;
  int tok = blockIdx.x * 4 + wave;
  const float* xr = x + (size_t)tok * DM;
  float acc[NE];
#pragma unroll
  for (int e = 0; e < NE; e++) acc[e] = 0.f;
  for (int d = lane; d < DM; d += 64) {
    float xv = xr[d];
    const float* g = gw + d * NE;
#pragma unroll
    for (int e = 0; e < NE; e++) acc[e] += xv * g[e];
  }
#pragma unroll
  for (int off = 32; off > 0; off >>= 1) {
#pragma unroll
    for (int e = 0; e < NE; e++) acc[e] += __shfl_down(acc[e], off);
  }
  if (lane == 0) {
    float l[NE], m = -1e30f;
#pragma unroll
    for (int e = 0; e < NE; e++) { l[e] = acc[e] + gb[e]; m = l[e] > m ? l[e] : m; }
    float p[NE], s = 0.f;
#pragma unroll
    for (int e = 0; e < NE; e++) { p[e] = expf(l[e] - m); s += p[e]; }
    float inv = 1.f / s;
    int e0 = 0; float s0 = p[0];
#pragma unroll
    for (int e = 1; e < NE; e++) if (p[e] > s0) { s0 = p[e]; e0 = e; }
    int e1 = -1; float s1 = -1.f;
#pragma unroll
    for (int e = 0; e < NE; e++) if (e != e0 && p[e] > s1) { s1 = p[e]; e1 = e; }
    s0 *= inv; s1 *= inv;
    int pos0 = atomicAdd(&cnt[e0], 1);
    lidx[e0 * NTOK + pos0] = tok; lw[e0 * NTOK + pos0] = s0;
    int pos1 = atomicAdd(&cnt[e1], 1);
    lidx[e1 * NTOK + pos1] = tok; lw[e1 * NTOK + pos1] = s1;
  }
}

__global__ void k_scan(const int* __restrict__ cnt, int* __restrict__ off) {
  if (threadIdx.x == 0) {
    int s = 0;
    for (int e = 0; e < NE; e++) { off[e] = s; s += cnt[e]; }
  }
}

// LDS layout (both GEMM kernels): tile element (row, k) lives at u16 offset
//   row*BK + ((kchunk ^ (row&7)) << 3) + (k&7)   where kchunk = k>>3.
// The XOR swizzle is applied on the GLOBAL source address per lane (the
// global_load_lds LDS dest is fixed at base + lane*16), and undone on the
// ds_read_b128 side. This turns the 16-way same-bank conflict of the
// unswizzled [row][k] layout (row stride = 128 B = 32 banks) into 2-way
// (free per m136).

// ---------- GEMM1: H[pair, f] = relu(Xb[idx] @ W1t^T + b1)  (K = DM) ----------
__global__ __launch_bounds__(256) void k_gemm1(const u16* __restrict__ xb, const u16* __restrict__ w1t,
                                               const float* __restrict__ b1, u16* __restrict__ H,
                                               const int* __restrict__ cnt, const int* __restrict__ offp,
                                               const int* __restrict__ lidx) {
  const int e = blockIdx.z;
  const int c = cnt[e];
  const int t0 = blockIdx.x * TM;
  if (t0 >= c) return;
  const int n0 = blockIdx.y * TN;

  __shared__ __align__(16) u16 smA[TM * BK];
  __shared__ __align__(16) u16 smB[TN * BK];

  const int tid = threadIdx.x;
  const int wave = tid >> 6, lane = tid & 63;
  const int sr = lane >> 3;
  const int skb = (((lane & 7) ^ sr) & 7) * 8;   // swizzled k-chunk source

  const u16* aPtr[4]; const u16* bPtr[4];
#pragma unroll
  for (int i = 0; i < 4; i++) {
    int ci = wave * 4 + i;
    int row = ci * 8 + sr;
    int p = t0 + row; p = p < c ? p : c - 1;
    int tk = lidx[e * NTOK + p];
    aPtr[i] = xb + (size_t)tk * DM + skb;
    bPtr[i] = w1t + ((size_t)e * DF + (n0 + row)) * DM + skb;
  }

  const int waveM = wave >> 1, waveN = wave & 1;
  const int c15 = lane & 15, quad = lane >> 4;
  const int r7 = c15 & 7;

  f32x4 acc[4][4];
#pragma unroll
  for (int mt = 0; mt < 4; mt++)
#pragma unroll
    for (int nt = 0; nt < 4; nt++) acc[mt][nt] = 0.f;

  for (int k0 = 0; k0 < DM; k0 += BK) {
#pragma unroll
    for (int i = 0; i < 4; i++) {
      async_copy16(aPtr[i], &smA[(wave * 4 + i) * 512]);
      async_copy16(bPtr[i], &smB[(wave * 4 + i) * 512]);
      aPtr[i] += BK; bPtr[i] += BK;
    }
    __syncthreads();
#pragma unroll
    for (int k2 = 0; k2 < BK; k2 += 32) {
      const int kcBase = k2 >> 3;   // 0 or 4
      const int koff = (((kcBase + quad) ^ r7) & 7) << 3;
      bf16x8 af[4], bfr[4];
#pragma unroll
      for (int mt = 0; mt < 4; mt++)
        af[mt] = *(const bf16x8*)&smA[(waveM * 64 + mt * 16 + c15) * BK + koff];
#pragma unroll
      for (int nt = 0; nt < 4; nt++)
        bfr[nt] = *(const bf16x8*)&smB[(waveN * 64 + nt * 16 + c15) * BK + koff];
#pragma unroll
      for (int mt = 0; mt < 4; mt++)
#pragma unroll
        for (int nt = 0; nt < 4; nt++)
          acc[mt][nt] = __builtin_amdgcn_mfma_f32_16x16x32_bf16(af[mt], bfr[nt], acc[mt][nt], 0, 0, 0);
    }
    __syncthreads();
  }

  const int hoff = offp[e];
#pragma unroll
  for (int mt = 0; mt < 4; mt++) {
#pragma unroll
    for (int r = 0; r < 4; r++) {
      int rowLoc = waveM * 64 + mt * 16 + quad * 4 + r;
      int p = t0 + rowLoc;
      if (p < c) {
        size_t hbase = (size_t)(hoff + p) * DF;
#pragma unroll
        for (int nt = 0; nt < 4; nt++) {
          int col = n0 + waveN * 64 + nt * 16 + c15;
          float v = acc[mt][nt][r] + b1[e * DF + col];
          H[hbase + col] = f2bf(v > 0.f ? v : 0.f);
        }
      }
    }
  }
}

// ---------- GEMM2: out[tok, d] += s * (H @ W2t^T + b2)  (K = DF) ----------
__global__ __launch_bounds__(256) void k_gemm2(const u16* __restrict__ H, const u16* __restrict__ w2t,
                                               const float* __restrict__ b2, float* __restrict__ out,
                                               const int* __restrict__ cnt, const int* __restrict__ offp,
                                               const int* __restrict__ lidx, const float* __restrict__ lw) {
  const int e = blockIdx.z;
  const int c = cnt[e];
  const int t0 = blockIdx.x * TM;
  if (t0 >= c) return;
  const int n0 = blockIdx.y * TN;
  const int hoff = offp[e];

  __shared__ __align__(16) u16 smA[TM * BK];
  __shared__ __align__(16) u16 smB[TN * BK];

  const int tid = threadIdx.x;
  const int wave = tid >> 6, lane = tid & 63;
  const int sr = lane >> 3;
  const int skb = (((lane & 7) ^ sr) & 7) * 8;   // swizzled k-chunk source

  const u16* aPtr[4]; const u16* bPtr[4];
#pragma unroll
  for (int i = 0; i < 4; i++) {
    int ci = wave * 4 + i;
    int row = ci * 8 + sr;
    int p = t0 + row; p = p < c ? p : c - 1;
    aPtr[i] = H + (size_t)(hoff + p) * DF + skb;
    bPtr[i] = w2t + ((size_t)e * DM + (n0 + row)) * DF + skb;
  }

  const int waveM = wave >> 1, waveN = wave & 1;
  const int c15 = lane & 15, quad = lane >> 4;
  const int r7 = c15 & 7;

  f32x4 acc[4][4];
#pragma unroll
  for (int mt = 0; mt < 4; mt++)
#pragma unroll
    for (int nt = 0; nt < 4; nt++) acc[mt][nt] = 0.f;

  for (int k0 = 0; k0 < DF; k0 += BK) {
#pragma unroll
    for (int i = 0; i < 4; i++) {
      async_copy16(aPtr[i], &smA[(wave * 4 + i) * 512]);
      async_copy16(bPtr[i], &smB[(wave * 4 + i) * 512]);
      aPtr[i] += BK; bPtr[i] += BK;
    }
    __syncthreads();
#pragma unroll
    for (int k2 = 0; k2 < BK; k2 += 32) {
      const int kcBase = k2 >> 3;
      const int koff = (((kcBase + quad) ^ r7) & 7) << 3;
      bf16x8 af[4], bfr[4];
#pragma unroll
      for (int mt = 0; mt < 4; mt++)
        af[mt] = *(const bf16x8*)&smA[(waveM * 64 + mt * 16 + c15) * BK + koff];
#pragma unroll
      for (int nt = 0; nt < 4; nt++)
        bfr[nt] = *(const bf16x8*)&smB[(waveN * 64 + nt * 16 + c15) * BK + koff];
#pragma unroll
      for (int mt = 0; mt < 4; mt++)
#pragma unroll
        for (int nt = 0; nt < 4; nt++)
          acc[mt][nt] = __builtin_amdgcn_mfma_f32_16x16x32_bf16(af[mt], bfr[nt], acc[mt][nt], 0, 0, 0);
    }
    __syncthreads();
  }

#pragma unroll
  for (int mt = 0; mt < 4; mt++) {
#pragma unroll
    for (int r = 0; r < 4; r++) {
      int rowLoc = waveM * 64 + mt * 16 + quad * 4 + r;
      int p = t0 + rowLoc;
      if (p < c) {
        int tok = lidx[e * NTOK + p];
        float wgt = lw[e * NTOK + p];
#pragma unroll
        for (int nt = 0; nt < 4; nt++) {
          int col = n0 + waveN * 64 + nt * 16 + c15;
          float v = wgt * (acc[mt][nt][r] + b2[e * DM + col]);
          atomicAdd(&out[(size_t)tok * DM + col], v);
        }
      }
    }
  }
}

extern "C" void kernel_launch(void* const* d_in, const int* in_sizes, int n_in,
                              void* d_out, int out_size, void* d_ws, size_t ws_size,
                              hipStream_t stream) {
  const float* x  = (const float*)d_in[0];
  const float* gw = (const float*)d_in[1];
  const float* gb = (const float*)d_in[2];
  const float* w1 = (const float*)d_in[3];
  const float* b1 = (const float*)d_in[4];
  const float* w2 = (const float*)d_in[5];
  const float* b2 = (const float*)d_in[6];
  float* out = (float*)d_out;

  char* ws = (char*)d_ws;
  // layout: xb (16 MiB) | wT (64 MiB, shared by w1t then w2t) | H (128 MiB) | lidx | lw | cnt | off
  u16* xb    = (u16*)(ws);
  u16* wT    = (u16*)(ws + 16777216);
  u16* H     = (u16*)(ws + 16777216 + 67108864);
  int* lidx  = (int*)(ws + 16777216 + 67108864 + 134217728);
  float* lw  = (float*)(ws + 16777216 + 67108864 + 134217728 + 262144);
  int* cnt   = (int*)(ws + 16777216 + 67108864 + 134217728 + 262144 + 262144);
  int* offp  = (int*)(ws + 16777216 + 67108864 + 134217728 + 262144 + 262144 + 128);

  hipMemsetAsync(cnt, 0, NE * sizeof(int), stream);
  hipMemsetAsync(out, 0, (size_t)out_size * sizeof(float), stream);

  k_cast_x<<<(NTOK * DM) / 1024, 256, 0, stream>>>(x, xb);
  k_gate<<<NTOK / 4, 256, 0, stream>>>(x, gw, gb, cnt, lidx, lw);
  k_scan<<<1, 64, 0, stream>>>(cnt, offp);

  // W1 [E][DM][DF] -> w1t [E][DF][DM]
  k_transpose_cast<<<dim3(DF / 32, DM / 32, NE), 256, 0, stream>>>(w1, wT, DM, DF);
  k_gemm1<<<dim3(NTOK / TM, DF / TN, NE), 256, 0, stream>>>(xb, wT, b1, H, cnt, offp, lidx);

  // W2 [E][DF][DM] -> w2t [E][DM][DF]  (reuses wT buffer; stream-ordered after gemm1)
  k_transpose_cast<<<dim3(DM / 32, DF / 32, NE), 256, 0, stream>>>(w2, wT, DF, DM);
  k_gemm2<<<dim3(NTOK / TM, DM / TN, NE), 256, 0, stream>>>(H, wT, b2, out, cnt, offp, lidx, lw);
}

// Round 3
// 1266.916 us; speedup vs baseline: 1.2021x; 1.0647x over previous
//
#include <hip/hip_runtime.h>
#include <stdint.h>
#include <stddef.h>

#define NTOK 8192
#define DM 1024
#define DF 4096
#define NE 8
#define TM 128
#define TN 128
#define BK 64
#define SMHALF (TM * BK)            // 8192 u16 = 16 KB
#define SMSTRIDE ((TM + TN) * BK)   // 16384 u16 = 32 KB per buffer

typedef unsigned short u16;
typedef __attribute__((ext_vector_type(8))) short bf16x8;
typedef __attribute__((ext_vector_type(4))) float f32x4;

__device__ __forceinline__ u16 f2bf(float f) {
  union { float f; unsigned u; } v; v.f = f;
  unsigned r = v.u + 0x7fffu + ((v.u >> 16) & 1u);
  return (u16)(r >> 16);
}

__device__ __forceinline__ void async_copy16(const void* g, void* l) {
  __builtin_amdgcn_global_load_lds((const __attribute__((address_space(1))) void*)g,
                                   (__attribute__((address_space(3))) void*)l, 16, 0, 0);
}

// Raw barrier / waitcnt: NO compiler-inserted vmcnt(0) drain. The prefetch
// loads stay in flight across the barrier (AITER-style pipeline).
__device__ __forceinline__ void raw_barrier() {
  __asm__ volatile("s_barrier" ::: "memory");
}
__device__ __forceinline__ void wait_vm8() {
  __asm__ volatile("s_waitcnt vmcnt(8)" ::: "memory");
}
__device__ __forceinline__ void wait_vm0() {
  __asm__ volatile("s_waitcnt vmcnt(0)" ::: "memory");
}

// ---------- cast x (fp32 -> bf16), 4 elems/thread ----------
__global__ __launch_bounds__(256) void k_cast_x(const float* __restrict__ x, u16* __restrict__ xb) {
  int i = (blockIdx.x * 256 + threadIdx.x) * 4;
  float4 v = *(const float4*)(x + i);
  ushort4 o;
  o.x = f2bf(v.x); o.y = f2bf(v.y); o.z = f2bf(v.z); o.w = f2bf(v.w);
  *(ushort4*)(xb + i) = o;
}

// ---------- transpose + cast weights: w [E][R][C] fp32 -> wt [E][C][R] bf16 ----------
__global__ __launch_bounds__(256) void k_transpose_cast(const float* __restrict__ w, u16* __restrict__ wt,
                                                        int R, int C) {
  __shared__ float tile[32][33];
  size_t base = (size_t)blockIdx.z * R * C;
  const float* wb = w + base;
  u16* wtb = wt + base;
  int c0 = blockIdx.x * 32, r0 = blockIdx.y * 32;
  int tx = threadIdx.x & 31, ty = threadIdx.x >> 5;
#pragma unroll
  for (int i = 0; i < 4; i++)
    tile[ty + i * 8][tx] = wb[(size_t)(r0 + ty + i * 8) * C + (c0 + tx)];
  __syncthreads();
#pragma unroll
  for (int i = 0; i < 4; i++)
    wtb[(size_t)(c0 + ty + i * 8) * R + (r0 + tx)] = f2bf(tile[tx][ty + i * 8]);
}

// ---------- gating: fp32 logits, softmax, top-2, routing lists ----------
__global__ __launch_bounds__(256) void k_gate(const float* __restrict__ x, const float* __restrict__ gw,
                                              const float* __restrict__ gb, int* __restrict__ cnt,
                                              int* __restrict__ lidx, float* __restrict__ lw) {
  int wave = threadIdx.x >> 6, lane = threadIdx.x & 63;
  int tok = blockIdx.x * 4 + wave;
  const float* xr = x + (size_t)tok * DM;
  float acc[NE];
#pragma unroll
  for (int e = 0; e < NE; e++) acc[e] = 0.f;
  for (int d = lane; d < DM; d += 64) {
    float xv = xr[d];
    const float* g = gw + d * NE;
#pragma unroll
    for (int e = 0; e < NE; e++) acc[e] += xv * g[e];
  }
#pragma unroll
  for (int off = 32; off > 0; off >>= 1) {
#pragma unroll
    for (int e = 0; e < NE; e++) acc[e] += __shfl_down(acc[e], off);
  }
  if (lane == 0) {
    float l[NE], m = -1e30f;
#pragma unroll
    for (int e = 0; e < NE; e++) { l[e] = acc[e] + gb[e]; m = l[e] > m ? l[e] : m; }
    float p[NE], s = 0.f;
#pragma unroll
    for (int e = 0; e < NE; e++) { p[e] = expf(l[e] - m); s += p[e]; }
    float inv = 1.f / s;
    int e0 = 0; float s0 = p[0];
#pragma unroll
    for (int e = 1; e < NE; e++) if (p[e] > s0) { s0 = p[e]; e0 = e; }
    int e1 = -1; float s1 = -1.f;
#pragma unroll
    for (int e = 0; e < NE; e++) if (e != e0 && p[e] > s1) { s1 = p[e]; e1 = e; }
    s0 *= inv; s1 *= inv;
    int pos0 = atomicAdd(&cnt[e0], 1);
    lidx[e0 * NTOK + pos0] = tok; lw[e0 * NTOK + pos0] = s0;
    int pos1 = atomicAdd(&cnt[e1], 1);
    lidx[e1 * NTOK + pos1] = tok; lw[e1 * NTOK + pos1] = s1;
  }
}

__global__ void k_scan(const int* __restrict__ cnt, int* __restrict__ off) {
  if (threadIdx.x == 0) {
    int s = 0;
    for (int e = 0; e < NE; e++) { off[e] = s; s += cnt[e]; }
  }
}

// LDS tile layout: element (row, k) at u16 offset row*BK + ((kc ^ (row&7))<<3) + (k&7),
// swizzle applied on the GLOBAL source address per lane, undone at ds_read.
// Double-buffered: sm[2][A(16KB)+B(16KB)]. K-loop: issue prefetch -> vmcnt(8)
// -> barrier -> MFMA -> barrier. No vmcnt(0) inside the loop.

#define STAGE(nb)                                                       \
  do {                                                                  \
    u16* dst = &smAll[(nb) * SMSTRIDE];                                 \
    _Pragma("unroll") for (int i = 0; i < 4; i++) {                     \
      async_copy16(aPtr[i], dst + (wave * 4 + i) * 512);                \
      async_copy16(bPtr[i], dst + SMHALF + (wave * 4 + i) * 512);       \
      aPtr[i] += BK; bPtr[i] += BK;                                     \
    }                                                                   \
  } while (0)

#define COMPUTE(cb)                                                         \
  do {                                                                      \
    const u16* bufA = &smAll[(cb) * SMSTRIDE];                              \
    const u16* bufB = bufA + SMHALF;                                        \
    _Pragma("unroll") for (int k2 = 0; k2 < BK; k2 += 32) {                 \
      const int koff = ((((k2 >> 3) + quad) ^ r7) & 7) << 3;                \
      bf16x8 af[4], bfr[4];                                                 \
      _Pragma("unroll") for (int mt = 0; mt < 4; mt++)                      \
        af[mt] = *(const bf16x8*)&bufA[(waveM * 64 + mt * 16 + c15) * BK + koff]; \
      _Pragma("unroll") for (int nt = 0; nt < 4; nt++)                      \
        bfr[nt] = *(const bf16x8*)&bufB[(waveN * 64 + nt * 16 + c15) * BK + koff]; \
      _Pragma("unroll") for (int mt = 0; mt < 4; mt++)                      \
        _Pragma("unroll") for (int nt = 0; nt < 4; nt++)                    \
          acc[mt][nt] = __builtin_amdgcn_mfma_f32_16x16x32_bf16(af[mt], bfr[nt], acc[mt][nt], 0, 0, 0); \
    }                                                                       \
  } while (0)

// ---------- GEMM1: H[pair, f] = relu(Xb[idx] @ W1t^T + b1)  (K = DM) ----------
__global__ __launch_bounds__(256) void k_gemm1(const u16* __restrict__ xb, const u16* __restrict__ w1t,
                                               const float* __restrict__ b1, u16* __restrict__ H,
                                               const int* __restrict__ cnt, const int* __restrict__ offp,
                                               const int* __restrict__ lidx) {
  const int e = blockIdx.z;
  const int c = cnt[e];
  const int t0 = blockIdx.x * TM;
  if (t0 >= c) return;
  const int n0 = blockIdx.y * TN;

  __shared__ __align__(16) u16 smAll[2 * SMSTRIDE];

  const int tid = threadIdx.x;
  const int wave = tid >> 6, lane = tid & 63;
  const int sr = lane >> 3;
  const int skb = (((lane & 7) ^ sr) & 7) * 8;

  const u16* aPtr[4]; const u16* bPtr[4];
#pragma unroll
  for (int i = 0; i < 4; i++) {
    int row = (wave * 4 + i) * 8 + sr;
    int p = t0 + row; p = p < c ? p : c - 1;
    int tk = lidx[e * NTOK + p];
    aPtr[i] = xb + (size_t)tk * DM + skb;
    bPtr[i] = w1t + ((size_t)e * DF + (n0 + row)) * DM + skb;
  }

  const int waveM = wave >> 1, waveN = wave & 1;
  const int c15 = lane & 15, quad = lane >> 4;
  const int r7 = c15 & 7;

  f32x4 acc[4][4];
#pragma unroll
  for (int mt = 0; mt < 4; mt++)
#pragma unroll
    for (int nt = 0; nt < 4; nt++) acc[mt][nt] = 0.f;

  STAGE(0);
  int cur = 0;
  for (int k0 = 0;; k0 += BK) {
    bool more = (k0 + BK < DM);
    if (more) { STAGE(cur ^ 1); wait_vm8(); }
    else      { wait_vm0(); }
    raw_barrier();
    COMPUTE(cur);
    if (!more) break;
    raw_barrier();
    cur ^= 1;
  }

  // Epilogue: stage bf16 tile in LDS (buf0 region; last compute read buf1),
  // then coalesced 16B stores.
  u16* st = &smAll[0];
  const int hoff = offp[e];
#pragma unroll
  for (int mt = 0; mt < 4; mt++)
#pragma unroll
    for (int r = 0; r < 4; r++) {
      int rowLoc = waveM * 64 + mt * 16 + quad * 4 + r;
#pragma unroll
      for (int nt = 0; nt < 4; nt++) {
        int colLoc = waveN * 64 + nt * 16 + c15;
        float v = acc[mt][nt][r] + b1[e * DF + n0 + colLoc];
        st[rowLoc * TN + colLoc] = f2bf(v > 0.f ? v : 0.f);
      }
    }
  __syncthreads();
#pragma unroll
  for (int it = 0; it < 8; it++) {
    int id = it * 256 + tid;
    int row = id >> 4, c16 = id & 15;
    int p = t0 + row;
    if (p < c)
      *(bf16x8*)&H[(size_t)(hoff + p) * DF + n0 + c16 * 8] =
          *(const bf16x8*)&st[row * TN + c16 * 8];
  }
}

// ---------- GEMM2: out[tok, d] += s * (H @ W2t^T + b2)  (K = DF) ----------
__global__ __launch_bounds__(256) void k_gemm2(const u16* __restrict__ H, const u16* __restrict__ w2t,
                                               const float* __restrict__ b2, float* __restrict__ out,
                                               const int* __restrict__ cnt, const int* __restrict__ offp,
                                               const int* __restrict__ lidx, const float* __restrict__ lw) {
  const int e = blockIdx.z;
  const int c = cnt[e];
  const int t0 = blockIdx.x * TM;
  if (t0 >= c) return;
  const int n0 = blockIdx.y * TN;
  const int hoff = offp[e];

  __shared__ __align__(16) u16 smAll[2 * SMSTRIDE];

  const int tid = threadIdx.x;
  const int wave = tid >> 6, lane = tid & 63;
  const int sr = lane >> 3;
  const int skb = (((lane & 7) ^ sr) & 7) * 8;

  const u16* aPtr[4]; const u16* bPtr[4];
#pragma unroll
  for (int i = 0; i < 4; i++) {
    int row = (wave * 4 + i) * 8 + sr;
    int p = t0 + row; p = p < c ? p : c - 1;
    aPtr[i] = H + (size_t)(hoff + p) * DF + skb;
    bPtr[i] = w2t + ((size_t)e * DM + (n0 + row)) * DF + skb;
  }

  const int waveM = wave >> 1, waveN = wave & 1;
  const int c15 = lane & 15, quad = lane >> 4;
  const int r7 = c15 & 7;

  f32x4 acc[4][4];
#pragma unroll
  for (int mt = 0; mt < 4; mt++)
#pragma unroll
    for (int nt = 0; nt < 4; nt++) acc[mt][nt] = 0.f;

  STAGE(0);
  int cur = 0;
  for (int k0 = 0;; k0 += BK) {
    bool more = (k0 + BK < DF);
    if (more) { STAGE(cur ^ 1); wait_vm8(); }
    else      { wait_vm0(); }
    raw_barrier();
    COMPUTE(cur);
    if (!more) break;
    raw_barrier();
    cur ^= 1;
  }

#pragma unroll
  for (int mt = 0; mt < 4; mt++) {
#pragma unroll
    for (int r = 0; r < 4; r++) {
      int rowLoc = waveM * 64 + mt * 16 + quad * 4 + r;
      int p = t0 + rowLoc;
      if (p < c) {
        int tok = lidx[e * NTOK + p];
        float wgt = lw[e * NTOK + p];
#pragma unroll
        for (int nt = 0; nt < 4; nt++) {
          int col = n0 + waveN * 64 + nt * 16 + c15;
          float v = wgt * (acc[mt][nt][r] + b2[e * DM + col]);
          atomicAdd(&out[(size_t)tok * DM + col], v);
        }
      }
    }
  }
}

extern "C" void kernel_launch(void* const* d_in, const int* in_sizes, int n_in,
                              void* d_out, int out_size, void* d_ws, size_t ws_size,
                              hipStream_t stream) {
  const float* x  = (const float*)d_in[0];
  const float* gw = (const float*)d_in[1];
  const float* gb = (const float*)d_in[2];
  const float* w1 = (const float*)d_in[3];
  const float* b1 = (const float*)d_in[4];
  const float* w2 = (const float*)d_in[5];
  const float* b2 = (const float*)d_in[6];
  float* out = (float*)d_out;

  char* ws = (char*)d_ws;
  u16* xb    = (u16*)(ws);
  u16* wT    = (u16*)(ws + 16777216);
  u16* H     = (u16*)(ws + 16777216 + 67108864);
  int* lidx  = (int*)(ws + 16777216 + 67108864 + 134217728);
  float* lw  = (float*)(ws + 16777216 + 67108864 + 134217728 + 262144);
  int* cnt   = (int*)(ws + 16777216 + 67108864 + 134217728 + 262144 + 262144);
  int* offp  = (int*)(ws + 16777216 + 67108864 + 134217728 + 262144 + 262144 + 128);

  hipMemsetAsync(cnt, 0, NE * sizeof(int), stream);
  hipMemsetAsync(out, 0, (size_t)out_size * sizeof(float), stream);

  k_cast_x<<<(NTOK * DM) / 1024, 256, 0, stream>>>(x, xb);
  k_gate<<<NTOK / 4, 256, 0, stream>>>(x, gw, gb, cnt, lidx, lw);
  k_scan<<<1, 64, 0, stream>>>(cnt, offp);

  // W1 [E][DM][DF] -> w1t [E][DF][DM]
  k_transpose_cast<<<dim3(DF / 32, DM / 32, NE), 256, 0, stream>>>(w1, wT, DM, DF);
  k_gemm1<<<dim3(NTOK / TM, DF / TN, NE), 256, 0, stream>>>(xb, wT, b1, H, cnt, offp, lidx);

  // W2 [E][DF][DM] -> w2t [E][DM][DF]
  k_transpose_cast<<<dim3(DM / 32, DF / 32, NE), 256, 0, stream>>>(w2, wT, DF, DM);
  k_gemm2<<<dim3(NTOK / TM, DM / TN, NE), 256, 0, stream>>>(H, wT, b2, out, cnt, offp, lidx, lw);
}

// Round 4
// 1030.197 us; speedup vs baseline: 1.4783x; 1.2298x over previous
//
#include <hip/hip_runtime.h>
#include <stdint.h>
#include <stddef.h>

#define NTOK 8192
#define DM 1024
#define DF 4096
#define NE 8
#define TM 128
#define TN 128
#define BK 64
#define MAXTILE 144
#define SMHALF (TM * BK)            // 8192 u16 = 16 KB
#define SMSTRIDE ((TM + TN) * BK)   // 16384 u16 = 32 KB per buffer

typedef unsigned short u16;
typedef __attribute__((ext_vector_type(8))) short bf16x8;
typedef __attribute__((ext_vector_type(4))) float f32x4;

__device__ __forceinline__ u16 f2bf(float f) {
  union { float f; unsigned u; } v; v.f = f;
  unsigned r = v.u + 0x7fffu + ((v.u >> 16) & 1u);
  return (u16)(r >> 16);
}

__device__ __forceinline__ void async_copy16(const void* g, void* l) {
  __builtin_amdgcn_global_load_lds((const __attribute__((address_space(1))) void*)g,
                                   (__attribute__((address_space(3))) void*)l, 16, 0, 0);
}

__device__ __forceinline__ void raw_barrier() {
  __asm__ volatile("s_barrier" ::: "memory");
}
__device__ __forceinline__ void wait_vm8() {
  __asm__ volatile("s_waitcnt vmcnt(8)" ::: "memory");
}
__device__ __forceinline__ void wait_vm0() {
  __asm__ volatile("s_waitcnt vmcnt(0)" ::: "memory");
}

// ---------- cast x (fp32 -> bf16) ----------
__global__ __launch_bounds__(256) void k_cast_x(const float* __restrict__ x, u16* __restrict__ xb) {
  int i = (blockIdx.x * 256 + threadIdx.x) * 4;
  float4 v = *(const float4*)(x + i);
  ushort4 o;
  o.x = f2bf(v.x); o.y = f2bf(v.y); o.z = f2bf(v.z); o.w = f2bf(v.w);
  *(ushort4*)(xb + i) = o;
}

// ---------- transpose + cast weights: w [E][R][C] fp32 -> wt [E][C][R] bf16 ----------
__global__ __launch_bounds__(256) void k_transpose_cast(const float* __restrict__ w, u16* __restrict__ wt,
                                                        int R, int C) {
  __shared__ float tile[32][33];
  size_t base = (size_t)blockIdx.z * R * C;
  const float* wb = w + base;
  u16* wtb = wt + base;
  int c0 = blockIdx.x * 32, r0 = blockIdx.y * 32;
  int tx = threadIdx.x & 31, ty = threadIdx.x >> 5;
#pragma unroll
  for (int i = 0; i < 4; i++)
    tile[ty + i * 8][tx] = wb[(size_t)(r0 + ty + i * 8) * C + (c0 + tx)];
  __syncthreads();
#pragma unroll
  for (int i = 0; i < 4; i++)
    wtb[(size_t)(c0 + ty + i * 8) * R + (r0 + tx)] = f2bf(tile[tx][ty + i * 8]);
}

// ---------- gating ----------
__global__ __launch_bounds__(256) void k_gate(const float* __restrict__ x, const float* __restrict__ gw,
                                              const float* __restrict__ gb, int* __restrict__ cnt,
                                              int* __restrict__ lidx, float* __restrict__ lw) {
  int wave = threadIdx.x >> 6, lane = threadIdx.x & 63;
  int tok = blockIdx.x * 4 + wave;
  const float* xr = x + (size_t)tok * DM;
  float acc[NE];
#pragma unroll
  for (int e = 0; e < NE; e++) acc[e] = 0.f;
  for (int d = lane; d < DM; d += 64) {
    float xv = xr[d];
    const float* g = gw + d * NE;
#pragma unroll
    for (int e = 0; e < NE; e++) acc[e] += xv * g[e];
  }
#pragma unroll
  for (int off = 32; off > 0; off >>= 1) {
#pragma unroll
    for (int e = 0; e < NE; e++) acc[e] += __shfl_down(acc[e], off);
  }
  if (lane == 0) {
    float l[NE], m = -1e30f;
#pragma unroll
    for (int e = 0; e < NE; e++) { l[e] = acc[e] + gb[e]; m = l[e] > m ? l[e] : m; }
    float p[NE], s = 0.f;
#pragma unroll
    for (int e = 0; e < NE; e++) { p[e] = expf(l[e] - m); s += p[e]; }
    float inv = 1.f / s;
    int e0 = 0; float s0 = p[0];
#pragma unroll
    for (int e = 1; e < NE; e++) if (p[e] > s0) { s0 = p[e]; e0 = e; }
    int e1 = -1; float s1 = -1.f;
#pragma unroll
    for (int e = 0; e < NE; e++) if (e != e0 && p[e] > s1) { s1 = p[e]; e1 = e; }
    s0 *= inv; s1 *= inv;
    int pos0 = atomicAdd(&cnt[e0], 1);
    lidx[e0 * NTOK + pos0] = tok; lw[e0 * NTOK + pos0] = s0;
    int pos1 = atomicAdd(&cnt[e1], 1);
    lidx[e1 * NTOK + pos1] = tok; lw[e1 * NTOK + pos1] = s1;
  }
}

// ---------- scan + row-tile map: tmap[t] = (e<<16) | rowTileWithinExpert ----------
__global__ void k_scan(const int* __restrict__ cnt, int* __restrict__ off,
                       int* __restrict__ tmap, int* __restrict__ ntile) {
  if (threadIdx.x == 0) {
    int s = 0, t = 0;
    for (int e = 0; e < NE; e++) {
      off[e] = s;
      int nt = (cnt[e] + TM - 1) / TM;
      for (int i = 0; i < nt; i++) tmap[t++] = (e << 16) | i;
      s += cnt[e];
    }
    ntile[0] = t;
  }
}

// LDS tile layout: element (row, k) at u16 offset row*BK + ((kc ^ (row&7))<<3) + (k&7),
// swizzle on the GLOBAL source address, undone at ds_read (2-way max = free).
// Double-buffered; K-loop: STAGE(next) -> vmcnt(8) -> barrier -> MFMA -> barrier.

#define STAGE(nb)                                                       \
  do {                                                                  \
    u16* dst = &smAll[(nb) * SMSTRIDE];                                 \
    _Pragma("unroll") for (int i = 0; i < 4; i++) {                     \
      async_copy16(aPtr[i], dst + (wave * 4 + i) * 512);                \
      async_copy16(bPtr[i], dst + SMHALF + (wave * 4 + i) * 512);       \
      aPtr[i] += BK; bPtr[i] += BK;                                     \
    }                                                                   \
  } while (0)

#define COMPUTE(cb)                                                         \
  do {                                                                      \
    const u16* bufA = &smAll[(cb) * SMSTRIDE];                              \
    const u16* bufB = bufA + SMHALF;                                        \
    _Pragma("unroll") for (int h = 0; h < 2; h++) {                         \
      const int koff = h ? koff1 : koff0;                                   \
      bf16x8 af[4], bfr[4];                                                 \
      _Pragma("unroll") for (int mt = 0; mt < 4; mt++)                      \
        af[mt] = *(const bf16x8*)&bufA[offA[mt] + koff];                    \
      _Pragma("unroll") for (int nt = 0; nt < 4; nt++)                      \
        bfr[nt] = *(const bf16x8*)&bufB[offB[nt] + koff];                   \
      _Pragma("unroll") for (int mt = 0; mt < 4; mt++)                      \
        _Pragma("unroll") for (int nt = 0; nt < 4; nt++)                    \
          acc[mt][nt] = __builtin_amdgcn_mfma_f32_16x16x32_bf16(af[mt], bfr[nt], acc[mt][nt], 0, 0, 0); \
    }                                                                       \
  } while (0)

#define FRAG_SETUP                                                      \
  const int waveM = wave >> 1, waveN = wave & 1;                        \
  const int c15 = lane & 15, quad = lane >> 4;                          \
  const int r7 = c15 & 7;                                               \
  const int koff0 = ((quad ^ r7) & 7) << 3;                             \
  const int koff1 = (((4 + quad) ^ r7) & 7) << 3;                       \
  int offA[4], offB[4];                                                 \
  _Pragma("unroll") for (int i = 0; i < 4; i++) {                       \
    offA[i] = (waveM * 64 + i * 16 + c15) * BK;                         \
    offB[i] = (waveN * 64 + i * 16 + c15) * BK;                         \
  }

// ---------- GEMM1: H[pair, f] = relu(Xb[idx] @ W1t^T + b1)  (K = DM) ----------
__global__ __launch_bounds__(256, 2) void k_gemm1(const u16* __restrict__ xb, const u16* __restrict__ w1t,
                                                  const float* __restrict__ b1, u16* __restrict__ H,
                                                  const int* __restrict__ cnt, const int* __restrict__ offp,
                                                  const int* __restrict__ lidx, const int* __restrict__ tmap,
                                                  const int* __restrict__ ntile) {
  if ((int)blockIdx.x >= ntile[0]) return;
  const int me = tmap[blockIdx.x];
  const int e = me >> 16;
  const int t0 = (me & 0xffff) * TM;
  const int c = cnt[e];
  const int n0 = blockIdx.y * TN;

  __shared__ __align__(16) u16 smAll[2 * SMSTRIDE];

  const int tid = threadIdx.x;
  const int wave = tid >> 6, lane = tid & 63;
  const int sr = lane >> 3;
  const int skb = (((lane & 7) ^ sr) & 7) * 8;

  const u16* aPtr[4]; const u16* bPtr[4];
#pragma unroll
  for (int i = 0; i < 4; i++) {
    int row = (wave * 4 + i) * 8 + sr;
    int p = t0 + row; p = p < c ? p : c - 1;
    int tk = lidx[e * NTOK + p];
    aPtr[i] = xb + (size_t)tk * DM + skb;
    bPtr[i] = w1t + ((size_t)e * DF + (n0 + row)) * DM + skb;
  }

  FRAG_SETUP

  f32x4 acc[4][4];
#pragma unroll
  for (int mt = 0; mt < 4; mt++)
#pragma unroll
    for (int nt = 0; nt < 4; nt++) acc[mt][nt] = 0.f;

  STAGE(0);
  int cur = 0;
  for (int k0 = 0;; k0 += BK) {
    bool more = (k0 + BK < DM);
    if (more) { STAGE(cur ^ 1); wait_vm8(); }
    else      { wait_vm0(); }
    raw_barrier();
    COMPUTE(cur);
    if (!more) break;
    raw_barrier();
    cur ^= 1;
  }

  // Epilogue via LDS (buf0; final compute read buf1), coalesced 16B stores.
  u16* st = &smAll[0];
  const int hoff = offp[e];
#pragma unroll
  for (int mt = 0; mt < 4; mt++)
#pragma unroll
    for (int r = 0; r < 4; r++) {
      int rowLoc = waveM * 64 + mt * 16 + quad * 4 + r;
#pragma unroll
      for (int nt = 0; nt < 4; nt++) {
        int colLoc = waveN * 64 + nt * 16 + c15;
        float v = acc[mt][nt][r] + b1[e * DF + n0 + colLoc];
        st[rowLoc * TN + colLoc] = f2bf(v > 0.f ? v : 0.f);
      }
    }
  __syncthreads();
#pragma unroll
  for (int it = 0; it < 8; it++) {
    int id = it * 256 + tid;
    int row = id >> 4, c16 = id & 15;
    int p = t0 + row;
    if (p < c)
      *(bf16x8*)&H[(size_t)(hoff + p) * DF + n0 + c16 * 8] =
          *(const bf16x8*)&st[row * TN + c16 * 8];
  }
}

// ---------- GEMM2: out[tok, d] += s * (H @ W2t^T + b2)  (K = DF) ----------
__global__ __launch_bounds__(256, 2) void k_gemm2(const u16* __restrict__ H, const u16* __restrict__ w2t,
                                                  const float* __restrict__ b2, float* __restrict__ out,
                                                  const int* __restrict__ cnt, const int* __restrict__ offp,
                                                  const int* __restrict__ lidx, const float* __restrict__ lw,
                                                  const int* __restrict__ tmap, const int* __restrict__ ntile) {
  if ((int)blockIdx.x >= ntile[0]) return;
  const int me = tmap[blockIdx.x];
  const int e = me >> 16;
  const int t0 = (me & 0xffff) * TM;
  const int c = cnt[e];
  const int n0 = blockIdx.y * TN;
  const int hoff = offp[e];

  __shared__ __align__(16) u16 smAll[2 * SMSTRIDE];

  const int tid = threadIdx.x;
  const int wave = tid >> 6, lane = tid & 63;
  const int sr = lane >> 3;
  const int skb = (((lane & 7) ^ sr) & 7) * 8;

  const u16* aPtr[4]; const u16* bPtr[4];
#pragma unroll
  for (int i = 0; i < 4; i++) {
    int row = (wave * 4 + i) * 8 + sr;
    int p = t0 + row; p = p < c ? p : c - 1;
    aPtr[i] = H + (size_t)(hoff + p) * DF + skb;
    bPtr[i] = w2t + ((size_t)e * DM + (n0 + row)) * DF + skb;
  }

  FRAG_SETUP

  f32x4 acc[4][4];
#pragma unroll
  for (int mt = 0; mt < 4; mt++)
#pragma unroll
    for (int nt = 0; nt < 4; nt++) acc[mt][nt] = 0.f;

  STAGE(0);
  int cur = 0;
  for (int k0 = 0;; k0 += BK) {
    bool more = (k0 + BK < DF);
    if (more) { STAGE(cur ^ 1); wait_vm8(); }
    else      { wait_vm0(); }
    raw_barrier();
    COMPUTE(cur);
    if (!more) break;
    raw_barrier();
    cur ^= 1;
  }

#pragma unroll
  for (int mt = 0; mt < 4; mt++) {
#pragma unroll
    for (int r = 0; r < 4; r++) {
      int rowLoc = waveM * 64 + mt * 16 + quad * 4 + r;
      int p = t0 + rowLoc;
      if (p < c) {
        int tok = lidx[e * NTOK + p];
        float wgt = lw[e * NTOK + p];
#pragma unroll
        for (int nt = 0; nt < 4; nt++) {
          int col = n0 + waveN * 64 + nt * 16 + c15;
          float v = wgt * (acc[mt][nt][r] + b2[e * DM + col]);
          atomicAdd(&out[(size_t)tok * DM + col], v);
        }
      }
    }
  }
}

extern "C" void kernel_launch(void* const* d_in, const int* in_sizes, int n_in,
                              void* d_out, int out_size, void* d_ws, size_t ws_size,
                              hipStream_t stream) {
  const float* x  = (const float*)d_in[0];
  const float* gw = (const float*)d_in[1];
  const float* gb = (const float*)d_in[2];
  const float* w1 = (const float*)d_in[3];
  const float* b1 = (const float*)d_in[4];
  const float* w2 = (const float*)d_in[5];
  const float* b2 = (const float*)d_in[6];
  float* out = (float*)d_out;

  char* ws = (char*)d_ws;
  u16* xb    = (u16*)(ws);
  u16* wT    = (u16*)(ws + 16777216);
  u16* H     = (u16*)(ws + 16777216 + 67108864);
  char* sm   = ws + 16777216 + 67108864 + 134217728;
  int* lidx  = (int*)(sm);
  float* lw  = (float*)(sm + 262144);
  int* cnt   = (int*)(sm + 524288);
  int* offp  = (int*)(sm + 524288 + 128);
  int* tmap  = (int*)(sm + 524288 + 256);
  int* ntile = (int*)(sm + 524288 + 256 + MAXTILE * 4);

  hipMemsetAsync(cnt, 0, NE * sizeof(int), stream);
  hipMemsetAsync(out, 0, (size_t)out_size * sizeof(float), stream);

  k_cast_x<<<(NTOK * DM) / 1024, 256, 0, stream>>>(x, xb);
  k_gate<<<NTOK / 4, 256, 0, stream>>>(x, gw, gb, cnt, lidx, lw);
  k_scan<<<1, 64, 0, stream>>>(cnt, offp, tmap, ntile);

  // W1 [E][DM][DF] -> w1t [E][DF][DM]
  k_transpose_cast<<<dim3(DF / 32, DM / 32, NE), 256, 0, stream>>>(w1, wT, DM, DF);
  k_gemm1<<<dim3(MAXTILE, DF / TN), 256, 0, stream>>>(xb, wT, b1, H, cnt, offp, lidx, tmap, ntile);

  // W2 [E][DF][DM] -> w2t [E][DM][DF]
  k_transpose_cast<<<dim3(DM / 32, DF / 32, NE), 256, 0, stream>>>(w2, wT, DF, DM);
  k_gemm2<<<dim3(MAXTILE, DM / TN), 256, 0, stream>>>(H, wT, b2, out, cnt, offp, lidx, lw, tmap, ntile);
}